// Round 8
// baseline (278.004 us; speedup 1.0000x reference)
//
#include <hip/hip_runtime.h>
#include <math.h>

#define L     2048
#define NFFT  4096
#define NH    2049          // half-spectrum bins
#define UST   2052          // row stride (in float2) for half-spectrum rows
#define D     32
#define B     32
#define KU    3
#define CCH   64            // recurrence chunk length
#define NCH   32            // L / CCH

// skewed LDS physical address (pad 1 float per 32)
__device__ __forceinline__ int PHY(int i) { return i + (i >> 5); }
// base-4 digit reversal of a 12-bit index
__device__ __forceinline__ int REV4(int i) {
  int r2 = __brev(i) >> 20;
  return ((r2 & 0x555) << 1) | ((r2 >> 1) & 0x555);
}

// ---------------------------------------------------------------- FFT cores
// Forward: 6 in-place radix-4 DIF stages. Natural in -> base4-digit-reversed out.
__device__ void dif6(float* sre, float* sim, const float2* __restrict__ tw, int tid) {
  #pragma unroll
  for (int st = 0; st < 6; ++st) {
    const int shift = 10 - 2 * st;       // log2(q), q = 1024 >> 2st
    const int q = 1 << shift;
    const int r = 1 << (2 * st);         // N/(4q)
    #pragma unroll
    for (int h = 0; h < 2; ++h) {
      const int idx = tid + h * 512;
      const int j = idx & (q - 1);
      const int g = idx >> shift;
      const int i0 = (g << (shift + 2)) + j;
      const int p0 = PHY(i0), p1 = PHY(i0 + q), p2 = PHY(i0 + 2 * q), p3 = PHY(i0 + 3 * q);
      float ax = sre[p0], ay = sim[p0], bx = sre[p1], by = sim[p1];
      float cx = sre[p2], cy = sim[p2], dx = sre[p3], dy = sim[p3];
      float t0x = ax + cx, t0y = ay + cy, t1x = ax - cx, t1y = ay - cy;
      float t2x = bx + dx, t2y = by + dy, t3x = bx - dx, t3y = by - dy;
      float2 w1 = tw[j * r];
      float w2x = w1.x * w1.x - w1.y * w1.y, w2y = 2.f * w1.x * w1.y;
      float w3x = w2x * w1.x - w2y * w1.y, w3y = w2x * w1.y + w2y * w1.x;
      sre[p0] = t0x + t2x; sim[p0] = t0y + t2y;
      float u1x = t1x + t3y, u1y = t1y - t3x;              // t1 - i*t3
      sre[p1] = u1x * w1.x - u1y * w1.y; sim[p1] = u1x * w1.y + u1y * w1.x;
      float u2x = t0x - t2x, u2y = t0y - t2y;
      sre[p2] = u2x * w2x - u2y * w2y; sim[p2] = u2x * w2y + u2y * w2x;
      float u3x = t1x - t3y, u3y = t1y + t3x;              // t1 + i*t3
      sre[p3] = u3x * w3x - u3y * w3y; sim[p3] = u3x * w3y + u3y * w3x;
    }
    __syncthreads();
  }
}

// Inverse: 6 in-place radix-4 DIT stages (transpose of DIF with conj twiddles).
// base4-digit-reversed in -> natural out. No 1/N scaling here.
__device__ void dit6(float* sre, float* sim, const float2* __restrict__ tw, int tid) {
  #pragma unroll
  for (int st = 0; st < 6; ++st) {
    const int shift = 2 * st;            // log2(q), q = 1<<2st
    const int q = 1 << shift;
    const int r = 1 << (10 - 2 * st);
    #pragma unroll
    for (int h = 0; h < 2; ++h) {
      const int idx = tid + h * 512;
      const int j = idx & (q - 1);
      const int g = idx >> shift;
      const int i0 = (g << (shift + 2)) + j;
      const int p0 = PHY(i0), p1 = PHY(i0 + q), p2 = PHY(i0 + 2 * q), p3 = PHY(i0 + 3 * q);
      float ax = sre[p0], ay = sim[p0], bx = sre[p1], by = sim[p1];
      float cx = sre[p2], cy = sim[p2], dx = sre[p3], dy = sim[p3];
      float2 w1 = tw[j * r]; w1.y = -w1.y;                 // conj
      float w2x = w1.x * w1.x - w1.y * w1.y, w2y = 2.f * w1.x * w1.y;
      float w3x = w2x * w1.x - w2y * w1.y, w3y = w2x * w1.y + w2y * w1.x;
      float bpx = bx * w1.x - by * w1.y, bpy = bx * w1.y + by * w1.x;
      float cpx = cx * w2x - cy * w2y,   cpy = cx * w2y + cy * w2x;
      float dpx = dx * w3x - dy * w3y,   dpy = dx * w3y + dy * w3x;
      float t0x = ax + cpx, t0y = ay + cpy, t1x = ax - cpx, t1y = ay - cpy;
      float t2x = bpx + dpx, t2y = bpy + dpy, t3x = bpx - dpx, t3y = bpy - dpy;
      sre[p0] = t0x + t2x; sim[p0] = t0y + t2y;
      sre[p1] = t1x - t3y; sim[p1] = t1y + t3x;            // t1 + i*t3
      sre[p2] = t0x - t2x; sim[p2] = t0y - t2y;
      sre[p3] = t1x + t3y; sim[p3] = t1y - t3x;            // t1 - i*t3
    }
    __syncthreads();
  }
}

// ---------------------------------------------------------------- transpose u (+ tw init)
// u (b, t, d) -> uTp rows (b*16+p) of float2 { u[t][2p], u[t][2p+1] }, t-major.
// Extra blocks (bx >= L/64, b==0) fill the twiddle table.
__global__ __launch_bounds__(256) void k_tr(const float* __restrict__ u,
                                            float2* __restrict__ uTp,
                                            float2* __restrict__ tw) {
  const int bx = blockIdx.x;
  const int b = blockIdx.y;
  const int tid = threadIdx.x;
  if (bx >= L / 64) {
    if (b == 0) {
      for (int jj = tid; jj < 2048; jj += 256) {
        int j = (bx - L / 64) * 2048 + jj;
        double ang = -2.0 * 3.14159265358979323846 * (double)j / (double)NFFT;
        tw[j] = make_float2((float)cos(ang), (float)sin(ang));
      }
    }
    return;
  }
  __shared__ float tile[64][33];
  const int t0 = bx * 64;
  for (int i = tid; i < 64 * 32; i += 256) {
    int tl = i >> 5, d = i & 31;
    tile[tl][d] = u[((size_t)b * L + t0 + tl) * D + d];
  }
  __syncthreads();
  for (int i = tid; i < 16 * 64; i += 256) {
    int p = i >> 6, tt = i & 63;
    uTp[((size_t)b * 16 + p) * L + t0 + tt] =
        make_float2(tile[tt][2 * p], tile[tt][2 * p + 1]);
  }
}

// ---------------------------------------------------------------- forward FFT
// blocks 0..511: u-pack (b,p): FFT of z = u[:,2p] + i*u[:,2p+1], unpack ->
//   Ubuf rows (b*32+2p), (b*32+2p+1), half-spectrum f<=2048.
// blocks 512..527: eigvec pack p2: unpack + eigval^0.25 scale -> Vf rows.
__global__ __launch_bounds__(512) void k_fft_fwd(const float2* __restrict__ uTp,
                                                 const float* __restrict__ eig_vecs,
                                                 const float* __restrict__ eig_vals,
                                                 const float2* __restrict__ tw,
                                                 float2* __restrict__ Ubuf,
                                                 float2* __restrict__ Vf) {
  __shared__ float sre[4224];
  __shared__ float sim[4224];
  const int blk = blockIdx.x;
  const int tid = threadIdx.x;
  if (blk < 512) {
    const float2* zp = uTp + (size_t)blk * L;
    for (int t = tid; t < L; t += 512) {
      float2 z = zp[t];
      int p = PHY(t);
      sre[p] = z.x; sim[p] = z.y;
    }
  } else {
    const int p2 = blk - 512;
    for (int t = tid; t < L; t += 512) {
      int p = PHY(t);
      sre[p] = eig_vecs[(size_t)t * D + 2 * p2];
      sim[p] = eig_vecs[(size_t)t * D + 2 * p2 + 1];
    }
  }
  for (int t = L + tid; t < NFFT; t += 512) {
    int p = PHY(t);
    sre[p] = 0.f; sim[p] = 0.f;
  }
  __syncthreads();
  dif6(sre, sim, tw, tid);
  // unpack: U_even = (A + conj(Ac))/2 ; U_odd = -i*(A - conj(Ac))/2
  if (blk < 512) {
    float2* r0 = Ubuf + (size_t)(2 * blk) * UST;       // row (b*32 + 2p)
    float2* r1 = r0 + UST;
    for (int f = tid; f <= 2048; f += 512) {
      int pa = PHY(REV4(f));
      int pc = PHY(REV4((NFFT - f) & (NFFT - 1)));
      float Ax = sre[pa], Ay = sim[pa];
      float Bx = sre[pc], By = -sim[pc];
      r0[f] = make_float2(0.5f * (Ax + Bx), 0.5f * (Ay + By));
      float Dx = Ax - Bx, Dy = Ay - By;
      r1[f] = make_float2(0.5f * Dy, -0.5f * Dx);
    }
  } else {
    const int p2 = blk - 512;
    const float sc0 = powf(eig_vals[2 * p2], 0.25f);
    const float sc1 = powf(eig_vals[2 * p2 + 1], 0.25f);
    float2* r0 = Vf + (size_t)(2 * p2) * UST;
    float2* r1 = r0 + UST;
    for (int f = tid; f <= 2048; f += 512) {
      int pa = PHY(REV4(f));
      int pc = PHY(REV4((NFFT - f) & (NFFT - 1)));
      float Ax = sre[pa], Ay = sim[pa];
      float Bx = sre[pc], By = -sim[pc];
      r0[f] = make_float2(0.5f * sc0 * (Ax + Bx), 0.5f * sc0 * (Ay + By));
      float Dx = Ax - Bx, Dy = Ay - By;
      r1[f] = make_float2(0.5f * sc1 * Dy, -0.5f * sc1 * Dx);
    }
  }
}

// ---------------------------------------------------------------- mix v4
// Q[b,o,f] = sum_d Ubuf[b,d,f] * W[f,d,o], W computed on the fly:
//   W[f,d,o] = sum_k Vf[k][f] * m_phi[(k*D+d)*D+o]
// Block: 256 threads = 32 o x 8 fi, FT=8 freqs; grid.y splits batches (2 ways,
// 16 batches / 2 chunk-iters per block) for occupancy/latency overlap.
#define FT 8
#define BC 8
__global__ __launch_bounds__(256) void k_mix(const float2* __restrict__ Ubuf,
                                             const float2* __restrict__ Vf,
                                             const float* __restrict__ m_phi,
                                             float2* __restrict__ Qbuf) {
  __shared__ float2 Ul[BC][D][FT];
  __shared__ float2 Qs[BC][D][FT];
  __shared__ float2 Vl[D][FT];
  const int f0 = blockIdx.x * FT;
  const int bbase = blockIdx.y * 16;       // 16 batches per block
  const int tid = threadIdx.x;
  const int o = tid & 31, fi = tid >> 5;
  const int f = f0 + fi;
  // stage Vl[k][ff] = Vf[k][f0+ff]
  {
    int k = tid >> 3, ff = tid & 7;
    int fff = f0 + ff;
    Vl[k][ff] = (fff < NH) ? Vf[(size_t)k * UST + fff] : make_float2(0.f, 0.f);
  }
  __syncthreads();
  // W fragment: Wr[d] = sum_k Vl[k][fi] * m_phi[(k*D+d)*D+o]
  // (fi-groups of a wave read identical m_phi addresses -> broadcast)
  float2 Wr[D];
  #pragma unroll
  for (int d = 0; d < D; ++d) Wr[d] = make_float2(0.f, 0.f);
  const float* mp = m_phi + o;
  for (int k = 0; k < D; ++k) {
    float2 v = Vl[k][fi];
    const float* mk = mp + (size_t)k * D * D;
    #pragma unroll
    for (int d = 0; d < D; ++d) {
      float m = mk[d * D];
      Wr[d].x += v.x * m;
      Wr[d].y += v.y * m;
    }
  }
  const int lf = tid & 7, row = tid >> 3;      // load/store roles
  for (int b0 = bbase; b0 < bbase + 16; b0 += BC) {
    __syncthreads();
    // stage U chunk: rows (b0+bc)*32+d, cols f0..f0+7 (64B per 8-lane group)
    #pragma unroll
    for (int it = 0; it < 8; ++it) {
      int r = row + it * 32;                   // 0..255
      int bc = r >> 5, d = r & 31;
      int ff = f0 + lf;
      Ul[bc][d][lf] = (ff < NH)
          ? Ubuf[((size_t)(b0 + bc) * D + d) * UST + ff]
          : make_float2(0.f, 0.f);
    }
    __syncthreads();
    // compute: thread (fi,o) does Q[b0+bc][o][f] = sum_d Ul[bc][d][fi]*Wr[d]
    #pragma unroll
    for (int bc = 0; bc < BC; ++bc) {
      float ax = 0.f, ay = 0.f;
      #pragma unroll
      for (int d = 0; d < D; ++d) {
        float2 uu = Ul[bc][d][fi];
        float2 ww = Wr[d];
        ax += uu.x * ww.x - uu.y * ww.y;
        ay += uu.x * ww.y + uu.y * ww.x;
      }
      Qs[bc][o][(fi + o) & 7] = make_float2(ax, ay);   // swizzled store
    }
    __syncthreads();
    // write out coalesced: row (b0+bc)*32+oo, cols f0..f0+7
    #pragma unroll
    for (int it = 0; it < 8; ++it) {
      int r = row + it * 32;
      int bc = r >> 5, oo = r & 31;
      int ff = f0 + lf;
      if (ff < NH)
        Qbuf[((size_t)(b0 + bc) * D + oo) * UST + ff] = Qs[bc][oo][(lf + oo) & 7];
    }
  }
}

// ---------------------------------------------------------------- inverse FFT
// block (b*16+q): packed ifft of Y = Q[2q] + i*Q[2q+1]; Hermitian-extend +
// digit-reverse fused into the load. Output dT rows (b*32+2q), (b*32+2q+1).
__global__ __launch_bounds__(512) void k_ifft(const float2* __restrict__ Qbuf,
                                              const float2* __restrict__ tw,
                                              float* __restrict__ dT) {
  __shared__ float sre[4224];
  __shared__ float sim[4224];
  const int blk = blockIdx.x;          // b*16 + q
  const int tid = threadIdx.x;
  const float2* r0 = Qbuf + (size_t)(2 * blk) * UST;
  const float2* r1 = r0 + UST;
  for (int f = tid; f <= 2048; f += 512) {
    float2 q1 = r0[f], q2 = r1[f];
    int pa = PHY(REV4(f));
    int pc = PHY(REV4((NFFT - f) & (NFFT - 1)));
    // Y[f] = q1 + i*q2 ; Y[N-f] = conj(q1) + i*conj(q2)
    sre[pa] = q1.x - q2.y; sim[pa] = q1.y + q2.x;
    sre[pc] = q1.x + q2.y; sim[pc] = -q1.y + q2.x;
  }
  __syncthreads();
  dit6(sre, sim, tw, tid);
  float* d0 = dT + (size_t)(2 * blk) * L;
  float* d1 = d0 + L;
  const float inv = 1.0f / (float)NFFT;
  for (int t = tid; t < L; t += 512) {
    int p = PHY(t);
    d0[t] = sre[p] * inv;
    d1[t] = sim[p] * inv;
  }
}

// ---------------------------------------------------------------- AR term
// delta[b,t,o] = dT[b,o,t] + sum_{k<=min(t,2)} sum_i m_u[o,i,k]*u[b,t-k,i]
#define TT 64
__global__ __launch_bounds__(256) void k_ar(const float* __restrict__ dT,
                                            const float* __restrict__ u,
                                            const float* __restrict__ m_u,
                                            float* __restrict__ delta) {
  __shared__ float Ds[D][TT + 1];
  __shared__ float Us[TT + 2][D];
  __shared__ float Mt[KU][D][D];      // [k][i][o]
  const int b = blockIdx.y;
  const int t0 = blockIdx.x * TT;
  const int tid = threadIdx.x;
  for (int idx = tid; idx < D * D * KU; idx += blockDim.x) {
    int k = idx % KU, i = (idx / KU) % D, o = idx / (KU * D);
    Mt[k][i][o] = m_u[idx];
  }
  for (int idx = tid; idx < D * TT; idx += blockDim.x) {
    int o = idx >> 6, tt = idx & 63;
    Ds[o][tt] = dT[((size_t)b * D + o) * L + t0 + tt];
  }
  for (int idx = tid; idx < (TT + 2) * D; idx += blockDim.x) {
    int j = idx >> 5, i = idx & 31;
    int t = t0 - 2 + j;
    Us[j][i] = (t >= 0) ? u[((size_t)b * L + t) * D + i] : 0.f;
  }
  __syncthreads();
  const int o = tid & 31, ts = tid >> 5;
  for (int tt = ts; tt < TT; tt += 8) {
    int t = t0 + tt;
    float acc = Ds[o][tt];
    #pragma unroll
    for (int k2 = 0; k2 < KU; ++k2) {
      if (t >= k2) {
        const float* ur = Us[tt + 2 - k2];
        #pragma unroll
        for (int i = 0; i < D; ++i) acc += Mt[k2][i][o] * ur[i];
      }
    }
    delta[((size_t)b * L + t) * D + o] = acc;
  }
}

// ---------------------------------------------------------------- recurrence
// Tc = T^64 where T = [[M0, M1], [I, 0]] (6 squarings)
__global__ __launch_bounds__(1024) void k_tc(const float* __restrict__ m_y,
                                             float* __restrict__ Tc) {
  __shared__ float A[64][68];
  __shared__ float Bb[64][68];
  const int tid = threadIdx.x;
  for (int idx = tid; idx < 64 * 64; idx += blockDim.x) {
    int r = idx >> 6, c = idx & 63;
    float v;
    if (r < 32) v = m_y[(r * 2 + (c >> 5)) * D + (c & 31)];
    else        v = (c == r - 32) ? 1.f : 0.f;
    A[r][c] = v;
  }
  __syncthreads();
  const int r = tid >> 4, cg = tid & 15;
  for (int it = 0; it < 6; ++it) {
    float4 acc = make_float4(0.f, 0.f, 0.f, 0.f);
    for (int i = 0; i < 64; ++i) {
      float a = A[r][i];
      float4 v = *(const float4*)&A[i][cg * 4];
      acc.x += a * v.x; acc.y += a * v.y; acc.z += a * v.z; acc.w += a * v.w;
    }
    __syncthreads();
    *(float4*)&Bb[r][cg * 4] = acc;
    __syncthreads();
    *(float4*)&A[r][cg * 4] = *(const float4*)&Bb[r][cg * 4];
    __syncthreads();
  }
  for (int idx = tid; idx < 64 * 64; idx += blockDim.x)
    Tc[idx] = A[idx >> 6][idx & 63];
}

// Phase A: zero-state chunk response; emit shat[b,c] = [y_{C-1}; y_{C-2}]
// v2: delta chunk staged in LDS so the serial chain has no global-load latency.
__global__ void k_scanA(const float* __restrict__ delta,
                        const float* __restrict__ m_y,
                        float* __restrict__ shat) {
  __shared__ float yb[2][D];
  __shared__ float Dl[CCH][D + 1];
  const int b = blockIdx.y, c = blockIdx.x;
  const int lane = threadIdx.x;            // 64 = one wave
  const int o = lane & 31, h = lane >> 5;
  float m0[16], m1[16];
  #pragma unroll
  for (int i = 0; i < 16; ++i) {
    m0[i] = m_y[(o * 2 + 0) * D + h * 16 + i];
    m1[i] = m_y[(o * 2 + 1) * D + h * 16 + i];
  }
  const float* dp = delta + ((size_t)b * L + c * CCH) * D;
  for (int j = lane; j < CCH * D / 4; j += 64) {
    float4 v = ((const float4*)dp)[j];
    int base = j * 4;
    int r = base >> 5, col = base & 31;
    Dl[r][col] = v.x; Dl[r][col + 1] = v.y;
    Dl[r][col + 2] = v.z; Dl[r][col + 3] = v.w;
  }
  if (lane < D) { yb[0][lane] = 0.f; yb[1][lane] = 0.f; }
  __syncthreads();
  float ylast = 0.f, yprev = 0.f;
  for (int r = 0; r < CCH; ++r) {
    const float* y1 = yb[(r + 1) & 1];
    const float* y2 = yb[r & 1];
    float acc = 0.f;
    #pragma unroll
    for (int i = 0; i < 16; ++i)
      acc += m0[i] * y1[h * 16 + i] + m1[i] * y2[h * 16 + i];
    acc += __shfl_xor(acc, 32);
    float y = acc + Dl[r][o];
    __syncthreads();
    if (h == 0) yb[r & 1][o] = y;
    __syncthreads();
    yprev = ylast; ylast = y;
  }
  if (h == 0) {
    float* sp = shat + ((size_t)b * NCH + c) * 64;
    sp[o] = ylast;
    sp[32 + o] = yprev;
  }
}

// Phase B: inter-chunk state scan, record incoming state per chunk.
__global__ void k_scanB(const float* __restrict__ Tc,
                        const float* __restrict__ shat,
                        float* __restrict__ sin_) {
  __shared__ float TcT[64][65];
  __shared__ float sb[64];
  const int b = blockIdx.x;
  const int r = threadIdx.x;               // 64
  for (int idx = r; idx < 64 * 64; idx += 64) {
    int rr = idx >> 6, cc = idx & 63;
    TcT[cc][rr] = Tc[idx];
  }
  sb[r] = 0.f;
  __syncthreads();
  for (int c = 0; c < NCH; ++c) {
    sin_[((size_t)b * NCH + c) * 64 + r] = sb[r];
    float acc = 0.f;
    #pragma unroll 8
    for (int i = 0; i < 64; ++i) acc += TcT[i][r] * sb[i];
    acc += shat[((size_t)b * NCH + c) * 64 + r];
    __syncthreads();
    sb[r] = acc;
    __syncthreads();
  }
}

// Phase C: re-run each chunk with true incoming state, write output.
// v2: delta chunk staged in LDS (same as scanA).
__global__ void k_scanC(const float* __restrict__ delta,
                        const float* __restrict__ m_y,
                        const float* __restrict__ sin_,
                        float* __restrict__ out) {
  __shared__ float yb[2][D];
  __shared__ float Dl[CCH][D + 1];
  const int b = blockIdx.y, c = blockIdx.x;
  const int lane = threadIdx.x;
  const int o = lane & 31, h = lane >> 5;
  float m0[16], m1[16];
  #pragma unroll
  for (int i = 0; i < 16; ++i) {
    m0[i] = m_y[(o * 2 + 0) * D + h * 16 + i];
    m1[i] = m_y[(o * 2 + 1) * D + h * 16 + i];
  }
  const float* dp = delta + ((size_t)b * L + c * CCH) * D;
  for (int j = lane; j < CCH * D / 4; j += 64) {
    float4 v = ((const float4*)dp)[j];
    int base = j * 4;
    int r = base >> 5, col = base & 31;
    Dl[r][col] = v.x; Dl[r][col + 1] = v.y;
    Dl[r][col + 2] = v.z; Dl[r][col + 3] = v.w;
  }
  const float* sp = sin_ + ((size_t)b * NCH + c) * 64;
  if (lane < 32) yb[1][lane] = sp[lane];        // y_{-1}
  else           yb[0][lane - 32] = sp[lane];   // y_{-2}
  __syncthreads();
  float* op = out + ((size_t)b * L + c * CCH) * D;
  for (int r = 0; r < CCH; ++r) {
    const float* y1 = yb[(r + 1) & 1];
    const float* y2 = yb[r & 1];
    float acc = 0.f;
    #pragma unroll
    for (int i = 0; i < 16; ++i)
      acc += m0[i] * y1[h * 16 + i] + m1[i] * y2[h * 16 + i];
    acc += __shfl_xor(acc, 32);
    float y = acc + Dl[r][o];
    __syncthreads();
    if (h == 0) { yb[r & 1][o] = y; op[r * D + o] = y; }
    __syncthreads();
  }
}

// ---------------------------------------------------------------- launch
extern "C" void kernel_launch(void* const* d_in, const int* in_sizes, int n_in,
                              void* d_out, int out_size, void* d_ws, size_t ws_size,
                              hipStream_t stream) {
  const float* u        = (const float*)d_in[0];
  const float* eig_vals = (const float*)d_in[1];
  const float* eig_vecs = (const float*)d_in[2];
  const float* m_u      = (const float*)d_in[3];
  const float* m_phi    = (const float*)d_in[4];
  const float* m_y      = (const float*)d_in[5];
  float* out = (float*)d_out;

  char* ws = (char*)d_ws;
  size_t off = 0;
  auto alloc = [&](size_t bytes) -> void* {
    void* p = ws + off;
    off += bytes;
    off = (off + 255) & ~(size_t)255;
    return p;
  };
  float2* tw   = (float2*)alloc((size_t)NFFT * sizeof(float2));           // 32 KB
  float2* uTp  = (float2*)alloc((size_t)B * 16 * L * sizeof(float2));     // 8.4 MB
  float2* Vf   = (float2*)alloc((size_t)D * UST * sizeof(float2));        // 0.5 MB
  float2* Ubuf = (float2*)alloc((size_t)B * D * UST * sizeof(float2));    // 16.8 MB
  float2* Qbuf = (float2*)alloc((size_t)B * D * UST * sizeof(float2));    // 16.8 MB
  float*  Tc   = (float*)alloc(64 * 64 * sizeof(float));
  float*  shat = (float*)alloc((size_t)B * NCH * 64 * sizeof(float));
  float*  sinb = (float*)alloc((size_t)B * NCH * 64 * sizeof(float));
  // aliases: dT reuses uTp (dead after k_fft_fwd); delta reuses Ubuf (dead after k_mix)
  float* dT    = (float*)uTp;
  float* delta = (float*)Ubuf;

  k_tr     <<<dim3(L / 64 + 2, B), 256, 0, stream>>>(u, uTp, tw);
  k_fft_fwd<<<528, 512, 0, stream>>>(uTp, eig_vecs, eig_vals, tw, Ubuf, Vf);
  k_mix    <<<dim3((NH + FT - 1) / FT, 2), 256, 0, stream>>>(Ubuf, Vf, m_phi, Qbuf);
  k_ifft   <<<B * 16, 512, 0, stream>>>(Qbuf, tw, dT);
  k_ar     <<<dim3(L / TT, B), 256, 0, stream>>>(dT, u, m_u, delta);
  k_tc     <<<1, 1024, 0, stream>>>(m_y, Tc);
  k_scanA  <<<dim3(NCH, B), 64, 0, stream>>>(delta, m_y, shat);
  k_scanB  <<<B, 64, 0, stream>>>(Tc, shat, sinb);
  k_scanC  <<<dim3(NCH, B), 64, 0, stream>>>(delta, m_y, sinb, out);
}

// Round 9
// 265.039 us; speedup vs baseline: 1.0489x; 1.0489x over previous
//
#include <hip/hip_runtime.h>
#include <math.h>

#define L     2048
#define NFFT  4096
#define NH    2049          // half-spectrum bins
#define UST   2052          // row stride (in float2) for half-spectrum rows
#define D     32
#define B     32
#define KU    3
#define CCH   64            // recurrence chunk length
#define NCH   32            // L / CCH

// skewed LDS physical address (pad 1 float per 32)
__device__ __forceinline__ int PHY(int i) { return i + (i >> 5); }
// base-4 digit reversal of a 12-bit index
__device__ __forceinline__ int REV4(int i) {
  int r2 = __brev(i) >> 20;
  return ((r2 & 0x555) << 1) | ((r2 >> 1) & 0x555);
}

// ---------------------------------------------------------------- FFT cores
// Forward: 6 in-place radix-4 DIF stages. Natural in -> base4-digit-reversed out.
__device__ void dif6(float* sre, float* sim, const float2* __restrict__ tw, int tid) {
  #pragma unroll
  for (int st = 0; st < 6; ++st) {
    const int shift = 10 - 2 * st;       // log2(q), q = 1024 >> 2st
    const int q = 1 << shift;
    const int r = 1 << (2 * st);         // N/(4q)
    #pragma unroll
    for (int h = 0; h < 2; ++h) {
      const int idx = tid + h * 512;
      const int j = idx & (q - 1);
      const int g = idx >> shift;
      const int i0 = (g << (shift + 2)) + j;
      const int p0 = PHY(i0), p1 = PHY(i0 + q), p2 = PHY(i0 + 2 * q), p3 = PHY(i0 + 3 * q);
      float ax = sre[p0], ay = sim[p0], bx = sre[p1], by = sim[p1];
      float cx = sre[p2], cy = sim[p2], dx = sre[p3], dy = sim[p3];
      float t0x = ax + cx, t0y = ay + cy, t1x = ax - cx, t1y = ay - cy;
      float t2x = bx + dx, t2y = by + dy, t3x = bx - dx, t3y = by - dy;
      float2 w1 = tw[j * r];
      float w2x = w1.x * w1.x - w1.y * w1.y, w2y = 2.f * w1.x * w1.y;
      float w3x = w2x * w1.x - w2y * w1.y, w3y = w2x * w1.y + w2y * w1.x;
      sre[p0] = t0x + t2x; sim[p0] = t0y + t2y;
      float u1x = t1x + t3y, u1y = t1y - t3x;              // t1 - i*t3
      sre[p1] = u1x * w1.x - u1y * w1.y; sim[p1] = u1x * w1.y + u1y * w1.x;
      float u2x = t0x - t2x, u2y = t0y - t2y;
      sre[p2] = u2x * w2x - u2y * w2y; sim[p2] = u2x * w2y + u2y * w2x;
      float u3x = t1x - t3y, u3y = t1y + t3x;              // t1 + i*t3
      sre[p3] = u3x * w3x - u3y * w3y; sim[p3] = u3x * w3y + u3y * w3x;
    }
    __syncthreads();
  }
}

// Inverse: 6 in-place radix-4 DIT stages (transpose of DIF with conj twiddles).
// base4-digit-reversed in -> natural out. No 1/N scaling here.
__device__ void dit6(float* sre, float* sim, const float2* __restrict__ tw, int tid) {
  #pragma unroll
  for (int st = 0; st < 6; ++st) {
    const int shift = 2 * st;            // log2(q), q = 1<<2st
    const int q = 1 << shift;
    const int r = 1 << (10 - 2 * st);
    #pragma unroll
    for (int h = 0; h < 2; ++h) {
      const int idx = tid + h * 512;
      const int j = idx & (q - 1);
      const int g = idx >> shift;
      const int i0 = (g << (shift + 2)) + j;
      const int p0 = PHY(i0), p1 = PHY(i0 + q), p2 = PHY(i0 + 2 * q), p3 = PHY(i0 + 3 * q);
      float ax = sre[p0], ay = sim[p0], bx = sre[p1], by = sim[p1];
      float cx = sre[p2], cy = sim[p2], dx = sre[p3], dy = sim[p3];
      float2 w1 = tw[j * r]; w1.y = -w1.y;                 // conj
      float w2x = w1.x * w1.x - w1.y * w1.y, w2y = 2.f * w1.x * w1.y;
      float w3x = w2x * w1.x - w2y * w1.y, w3y = w2x * w1.y + w2y * w1.x;
      float bpx = bx * w1.x - by * w1.y, bpy = bx * w1.y + by * w1.x;
      float cpx = cx * w2x - cy * w2y,   cpy = cx * w2y + cy * w2x;
      float dpx = dx * w3x - dy * w3y,   dpy = dx * w3y + dy * w3x;
      float t0x = ax + cpx, t0y = ay + cpy, t1x = ax - cpx, t1y = ay - cpy;
      float t2x = bpx + dpx, t2y = bpy + dpy, t3x = bpx - dpx, t3y = bpy - dpy;
      sre[p0] = t0x + t2x; sim[p0] = t0y + t2y;
      sre[p1] = t1x - t3y; sim[p1] = t1y + t3x;            // t1 + i*t3
      sre[p2] = t0x - t2x; sim[p2] = t0y - t2y;
      sre[p3] = t1x + t3y; sim[p3] = t1y - t3x;            // t1 - i*t3
    }
    __syncthreads();
  }
}

// ---------------------------------------------------------------- transpose u (+ tw init)
// u (b, t, d) -> uTp rows (b*16+p) of float2 { u[t][2p], u[t][2p+1] }, t-major.
// Extra blocks (bx >= L/64, b==0) fill the twiddle table.
__global__ __launch_bounds__(256) void k_tr(const float* __restrict__ u,
                                            float2* __restrict__ uTp,
                                            float2* __restrict__ tw) {
  const int bx = blockIdx.x;
  const int b = blockIdx.y;
  const int tid = threadIdx.x;
  if (bx >= L / 64) {
    if (b == 0) {
      for (int jj = tid; jj < 2048; jj += 256) {
        int j = (bx - L / 64) * 2048 + jj;
        double ang = -2.0 * 3.14159265358979323846 * (double)j / (double)NFFT;
        tw[j] = make_float2((float)cos(ang), (float)sin(ang));
      }
    }
    return;
  }
  __shared__ float tile[64][33];
  const int t0 = bx * 64;
  for (int i = tid; i < 64 * 32; i += 256) {
    int tl = i >> 5, d = i & 31;
    tile[tl][d] = u[((size_t)b * L + t0 + tl) * D + d];
  }
  __syncthreads();
  for (int i = tid; i < 16 * 64; i += 256) {
    int p = i >> 6, tt = i & 63;
    uTp[((size_t)b * 16 + p) * L + t0 + tt] =
        make_float2(tile[tt][2 * p], tile[tt][2 * p + 1]);
  }
}

// ---------------------------------------------------------------- forward FFT
// blocks 0..511: u-pack (b,p): FFT of z = u[:,2p] + i*u[:,2p+1], unpack ->
//   Ubuf rows (b*32+2p), (b*32+2p+1), half-spectrum f<=2048.
// blocks 512..527: eigvec pack p2: unpack + eigval^0.25 scale -> Vf rows.
__global__ __launch_bounds__(512) void k_fft_fwd(const float2* __restrict__ uTp,
                                                 const float* __restrict__ eig_vecs,
                                                 const float* __restrict__ eig_vals,
                                                 const float2* __restrict__ tw,
                                                 float2* __restrict__ Ubuf,
                                                 float2* __restrict__ Vf) {
  __shared__ float sre[4224];
  __shared__ float sim[4224];
  const int blk = blockIdx.x;
  const int tid = threadIdx.x;
  if (blk < 512) {
    const float2* zp = uTp + (size_t)blk * L;
    for (int t = tid; t < L; t += 512) {
      float2 z = zp[t];
      int p = PHY(t);
      sre[p] = z.x; sim[p] = z.y;
    }
  } else {
    const int p2 = blk - 512;
    for (int t = tid; t < L; t += 512) {
      int p = PHY(t);
      sre[p] = eig_vecs[(size_t)t * D + 2 * p2];
      sim[p] = eig_vecs[(size_t)t * D + 2 * p2 + 1];
    }
  }
  for (int t = L + tid; t < NFFT; t += 512) {
    int p = PHY(t);
    sre[p] = 0.f; sim[p] = 0.f;
  }
  __syncthreads();
  dif6(sre, sim, tw, tid);
  // unpack: U_even = (A + conj(Ac))/2 ; U_odd = -i*(A - conj(Ac))/2
  if (blk < 512) {
    float2* r0 = Ubuf + (size_t)(2 * blk) * UST;       // row (b*32 + 2p)
    float2* r1 = r0 + UST;
    for (int f = tid; f <= 2048; f += 512) {
      int pa = PHY(REV4(f));
      int pc = PHY(REV4((NFFT - f) & (NFFT - 1)));
      float Ax = sre[pa], Ay = sim[pa];
      float Bx = sre[pc], By = -sim[pc];
      r0[f] = make_float2(0.5f * (Ax + Bx), 0.5f * (Ay + By));
      float Dx = Ax - Bx, Dy = Ay - By;
      r1[f] = make_float2(0.5f * Dy, -0.5f * Dx);
    }
  } else {
    const int p2 = blk - 512;
    const float sc0 = powf(eig_vals[2 * p2], 0.25f);
    const float sc1 = powf(eig_vals[2 * p2 + 1], 0.25f);
    float2* r0 = Vf + (size_t)(2 * p2) * UST;
    float2* r1 = r0 + UST;
    for (int f = tid; f <= 2048; f += 512) {
      int pa = PHY(REV4(f));
      int pc = PHY(REV4((NFFT - f) & (NFFT - 1)));
      float Ax = sre[pa], Ay = sim[pa];
      float Bx = sre[pc], By = -sim[pc];
      r0[f] = make_float2(0.5f * sc0 * (Ax + Bx), 0.5f * sc0 * (Ay + By));
      float Dx = Ax - Bx, Dy = Ay - By;
      r1[f] = make_float2(0.5f * sc1 * Dy, -0.5f * sc1 * Dx);
    }
  }
}

// ---------------------------------------------------------------- W build (tiled)
// Wm[f,d,o] = sum_k Vf[k][f] * m_phi[(k*D+d)*D+o]
// 257 blocks x 8 f's (block 256 = Nyquist only). m_phi staged via LDS in
// 4 chunks of 8dx32o; V tile in LDS; per-thread m[] column in registers.
#define KWFT 8
__global__ __launch_bounds__(256) void k_w(const float2* __restrict__ Vf,
                                           const float* __restrict__ m_phi,
                                           float2* __restrict__ Wm) {
  __shared__ float2 Vl[D][KWFT];        // [k][f_local]
  __shared__ float  Ml[D][256];         // [k][d_local*32+o]
  const int f0 = blockIdx.x * KWFT;
  const int tid = threadIdx.x;
  {
    int k = tid >> 3, ff = tid & 7;
    int f = f0 + ff;
    Vl[k][ff] = (f < NH) ? Vf[(size_t)k * UST + f] : make_float2(0.f, 0.f);
  }
  for (int c = 0; c < 4; ++c) {         // d-chunks: d = c*8 .. c*8+7
    __syncthreads();
    for (int i = tid; i < D * 256; i += 256) {
      int k = i >> 8, doo = i & 255;
      Ml[k][doo] = m_phi[(size_t)k * D * D + c * 256 + doo];
    }
    __syncthreads();
    float m[D];
    #pragma unroll
    for (int k = 0; k < D; ++k) m[k] = Ml[k][tid];
    const int d = c * 8 + (tid >> 5), o = tid & 31;
    #pragma unroll
    for (int ff = 0; ff < KWFT; ++ff) {
      int f = f0 + ff;
      if (f >= NH) break;
      float2 acc = make_float2(0.f, 0.f);
      #pragma unroll
      for (int k = 0; k < D; ++k) {
        float2 v = Vl[k][ff];
        acc.x += v.x * m[k];
        acc.y += v.y * m[k];
      }
      Wm[(size_t)f * D * D + d * D + o] = acc;
    }
  }
}

// ---------------------------------------------------------------- mix v5
// Q[b,o,f] = sum_d Ubuf[b,d,f] * Wm[f,d,o], half-spectrum only.
// W loaded coalesced from precomputed Wm (once per block); batch-split grid.y.
#define FT 8
#define BC 8
__global__ __launch_bounds__(256) void k_mix(const float2* __restrict__ Ubuf,
                                             const float2* __restrict__ Wm,
                                             float2* __restrict__ Qbuf) {
  __shared__ float2 Ul[BC][D][FT];
  __shared__ float2 Qs[BC][D][FT];
  const int f0 = blockIdx.x * FT;
  const int bbase = blockIdx.y * 16;       // 16 batches per block
  const int tid = threadIdx.x;
  const int o = tid & 31, fi = tid >> 5;
  const int f = f0 + fi;
  // W fragment into registers: Wr[d] = Wm[f][d][o] (coalesced across o)
  float2 Wr[D];
  if (f < NH) {
    const float2* wp = Wm + (size_t)f * D * D + o;
    #pragma unroll
    for (int d = 0; d < D; ++d) Wr[d] = wp[d * D];
  } else {
    #pragma unroll
    for (int d = 0; d < D; ++d) Wr[d] = make_float2(0.f, 0.f);
  }
  const int lf = tid & 7, row = tid >> 3;      // load/store roles
  for (int b0 = bbase; b0 < bbase + 16; b0 += BC) {
    __syncthreads();
    // stage U chunk: rows (b0+bc)*32+d, cols f0..f0+7 (64B per 8-lane group)
    #pragma unroll
    for (int it = 0; it < 8; ++it) {
      int r = row + it * 32;                   // 0..255
      int bc = r >> 5, d = r & 31;
      int ff = f0 + lf;
      Ul[bc][d][lf] = (ff < NH)
          ? Ubuf[((size_t)(b0 + bc) * D + d) * UST + ff]
          : make_float2(0.f, 0.f);
    }
    __syncthreads();
    // compute: thread (fi,o) does Q[b0+bc][o][f] = sum_d Ul[bc][d][fi]*Wr[d]
    #pragma unroll
    for (int bc = 0; bc < BC; ++bc) {
      float ax = 0.f, ay = 0.f;
      #pragma unroll
      for (int d = 0; d < D; ++d) {
        float2 uu = Ul[bc][d][fi];
        float2 ww = Wr[d];
        ax += uu.x * ww.x - uu.y * ww.y;
        ay += uu.x * ww.y + uu.y * ww.x;
      }
      Qs[bc][o][(fi + o) & 7] = make_float2(ax, ay);   // swizzled store
    }
    __syncthreads();
    // write out coalesced: row (b0+bc)*32+oo, cols f0..f0+7
    #pragma unroll
    for (int it = 0; it < 8; ++it) {
      int r = row + it * 32;
      int bc = r >> 5, oo = r & 31;
      int ff = f0 + lf;
      if (ff < NH)
        Qbuf[((size_t)(b0 + bc) * D + oo) * UST + ff] = Qs[bc][oo][(lf + oo) & 7];
    }
  }
}

// ---------------------------------------------------------------- inverse FFT
// block (b*16+q): packed ifft of Y = Q[2q] + i*Q[2q+1]; Hermitian-extend +
// digit-reverse fused into the load. Output dT rows (b*32+2q), (b*32+2q+1).
__global__ __launch_bounds__(512) void k_ifft(const float2* __restrict__ Qbuf,
                                              const float2* __restrict__ tw,
                                              float* __restrict__ dT) {
  __shared__ float sre[4224];
  __shared__ float sim[4224];
  const int blk = blockIdx.x;          // b*16 + q
  const int tid = threadIdx.x;
  const float2* r0 = Qbuf + (size_t)(2 * blk) * UST;
  const float2* r1 = r0 + UST;
  for (int f = tid; f <= 2048; f += 512) {
    float2 q1 = r0[f], q2 = r1[f];
    int pa = PHY(REV4(f));
    int pc = PHY(REV4((NFFT - f) & (NFFT - 1)));
    // Y[f] = q1 + i*q2 ; Y[N-f] = conj(q1) + i*conj(q2)
    sre[pa] = q1.x - q2.y; sim[pa] = q1.y + q2.x;
    sre[pc] = q1.x + q2.y; sim[pc] = -q1.y + q2.x;
  }
  __syncthreads();
  dit6(sre, sim, tw, tid);
  float* d0 = dT + (size_t)(2 * blk) * L;
  float* d1 = d0 + L;
  const float inv = 1.0f / (float)NFFT;
  for (int t = tid; t < L; t += 512) {
    int p = PHY(t);
    d0[t] = sre[p] * inv;
    d1[t] = sim[p] * inv;
  }
}

// ---------------------------------------------------------------- AR term
// delta[b,t,o] = dT[b,o,t] + sum_{k<=min(t,2)} sum_i m_u[o,i,k]*u[b,t-k,i]
#define TT 64
__global__ __launch_bounds__(256) void k_ar(const float* __restrict__ dT,
                                            const float* __restrict__ u,
                                            const float* __restrict__ m_u,
                                            float* __restrict__ delta) {
  __shared__ float Ds[D][TT + 1];
  __shared__ float Us[TT + 2][D];
  __shared__ float Mt[KU][D][D];      // [k][i][o]
  const int b = blockIdx.y;
  const int t0 = blockIdx.x * TT;
  const int tid = threadIdx.x;
  for (int idx = tid; idx < D * D * KU; idx += blockDim.x) {
    int k = idx % KU, i = (idx / KU) % D, o = idx / (KU * D);
    Mt[k][i][o] = m_u[idx];
  }
  for (int idx = tid; idx < D * TT; idx += blockDim.x) {
    int o = idx >> 6, tt = idx & 63;
    Ds[o][tt] = dT[((size_t)b * D + o) * L + t0 + tt];
  }
  for (int idx = tid; idx < (TT + 2) * D; idx += blockDim.x) {
    int j = idx >> 5, i = idx & 31;
    int t = t0 - 2 + j;
    Us[j][i] = (t >= 0) ? u[((size_t)b * L + t) * D + i] : 0.f;
  }
  __syncthreads();
  const int o = tid & 31, ts = tid >> 5;
  for (int tt = ts; tt < TT; tt += 8) {
    int t = t0 + tt;
    float acc = Ds[o][tt];
    #pragma unroll
    for (int k2 = 0; k2 < KU; ++k2) {
      if (t >= k2) {
        const float* ur = Us[tt + 2 - k2];
        #pragma unroll
        for (int i = 0; i < D; ++i) acc += Mt[k2][i][o] * ur[i];
      }
    }
    delta[((size_t)b * L + t) * D + o] = acc;
  }
}

// ---------------------------------------------------------------- recurrence
// Tc = T^64 where T = [[M0, M1], [I, 0]] (6 squarings)
__global__ __launch_bounds__(1024) void k_tc(const float* __restrict__ m_y,
                                             float* __restrict__ Tc) {
  __shared__ float A[64][68];
  __shared__ float Bb[64][68];
  const int tid = threadIdx.x;
  for (int idx = tid; idx < 64 * 64; idx += blockDim.x) {
    int r = idx >> 6, c = idx & 63;
    float v;
    if (r < 32) v = m_y[(r * 2 + (c >> 5)) * D + (c & 31)];
    else        v = (c == r - 32) ? 1.f : 0.f;
    A[r][c] = v;
  }
  __syncthreads();
  const int r = tid >> 4, cg = tid & 15;
  for (int it = 0; it < 6; ++it) {
    float4 acc = make_float4(0.f, 0.f, 0.f, 0.f);
    for (int i = 0; i < 64; ++i) {
      float a = A[r][i];
      float4 v = *(const float4*)&A[i][cg * 4];
      acc.x += a * v.x; acc.y += a * v.y; acc.z += a * v.z; acc.w += a * v.w;
    }
    __syncthreads();
    *(float4*)&Bb[r][cg * 4] = acc;
    __syncthreads();
    *(float4*)&A[r][cg * 4] = *(const float4*)&Bb[r][cg * 4];
    __syncthreads();
  }
  for (int idx = tid; idx < 64 * 64; idx += blockDim.x)
    Tc[idx] = A[idx >> 6][idx & 63];
}

// Phase A: zero-state chunk response; emit shat[b,c] = [y_{C-1}; y_{C-2}]
// v2: delta chunk staged in LDS so the serial chain has no global-load latency.
__global__ void k_scanA(const float* __restrict__ delta,
                        const float* __restrict__ m_y,
                        float* __restrict__ shat) {
  __shared__ float yb[2][D];
  __shared__ float Dl[CCH][D + 1];
  const int b = blockIdx.y, c = blockIdx.x;
  const int lane = threadIdx.x;            // 64 = one wave
  const int o = lane & 31, h = lane >> 5;
  float m0[16], m1[16];
  #pragma unroll
  for (int i = 0; i < 16; ++i) {
    m0[i] = m_y[(o * 2 + 0) * D + h * 16 + i];
    m1[i] = m_y[(o * 2 + 1) * D + h * 16 + i];
  }
  const float* dp = delta + ((size_t)b * L + c * CCH) * D;
  for (int j = lane; j < CCH * D / 4; j += 64) {
    float4 v = ((const float4*)dp)[j];
    int base = j * 4;
    int r = base >> 5, col = base & 31;
    Dl[r][col] = v.x; Dl[r][col + 1] = v.y;
    Dl[r][col + 2] = v.z; Dl[r][col + 3] = v.w;
  }
  if (lane < D) { yb[0][lane] = 0.f; yb[1][lane] = 0.f; }
  __syncthreads();
  float ylast = 0.f, yprev = 0.f;
  for (int r = 0; r < CCH; ++r) {
    const float* y1 = yb[(r + 1) & 1];
    const float* y2 = yb[r & 1];
    float acc = 0.f;
    #pragma unroll
    for (int i = 0; i < 16; ++i)
      acc += m0[i] * y1[h * 16 + i] + m1[i] * y2[h * 16 + i];
    acc += __shfl_xor(acc, 32);
    float y = acc + Dl[r][o];
    __syncthreads();
    if (h == 0) yb[r & 1][o] = y;
    __syncthreads();
    yprev = ylast; ylast = y;
  }
  if (h == 0) {
    float* sp = shat + ((size_t)b * NCH + c) * 64;
    sp[o] = ylast;
    sp[32 + o] = yprev;
  }
}

// Phase B: inter-chunk state scan, record incoming state per chunk.
__global__ void k_scanB(const float* __restrict__ Tc,
                        const float* __restrict__ shat,
                        float* __restrict__ sin_) {
  __shared__ float TcT[64][65];
  __shared__ float sb[64];
  const int b = blockIdx.x;
  const int r = threadIdx.x;               // 64
  for (int idx = r; idx < 64 * 64; idx += 64) {
    int rr = idx >> 6, cc = idx & 63;
    TcT[cc][rr] = Tc[idx];
  }
  sb[r] = 0.f;
  __syncthreads();
  for (int c = 0; c < NCH; ++c) {
    sin_[((size_t)b * NCH + c) * 64 + r] = sb[r];
    float acc = 0.f;
    #pragma unroll 8
    for (int i = 0; i < 64; ++i) acc += TcT[i][r] * sb[i];
    acc += shat[((size_t)b * NCH + c) * 64 + r];
    __syncthreads();
    sb[r] = acc;
    __syncthreads();
  }
}

// Phase C: re-run each chunk with true incoming state, write output.
// v2: delta chunk staged in LDS (same as scanA).
__global__ void k_scanC(const float* __restrict__ delta,
                        const float* __restrict__ m_y,
                        const float* __restrict__ sin_,
                        float* __restrict__ out) {
  __shared__ float yb[2][D];
  __shared__ float Dl[CCH][D + 1];
  const int b = blockIdx.y, c = blockIdx.x;
  const int lane = threadIdx.x;
  const int o = lane & 31, h = lane >> 5;
  float m0[16], m1[16];
  #pragma unroll
  for (int i = 0; i < 16; ++i) {
    m0[i] = m_y[(o * 2 + 0) * D + h * 16 + i];
    m1[i] = m_y[(o * 2 + 1) * D + h * 16 + i];
  }
  const float* dp = delta + ((size_t)b * L + c * CCH) * D;
  for (int j = lane; j < CCH * D / 4; j += 64) {
    float4 v = ((const float4*)dp)[j];
    int base = j * 4;
    int r = base >> 5, col = base & 31;
    Dl[r][col] = v.x; Dl[r][col + 1] = v.y;
    Dl[r][col + 2] = v.z; Dl[r][col + 3] = v.w;
  }
  const float* sp = sin_ + ((size_t)b * NCH + c) * 64;
  if (lane < 32) yb[1][lane] = sp[lane];        // y_{-1}
  else           yb[0][lane - 32] = sp[lane];   // y_{-2}
  __syncthreads();
  float* op = out + ((size_t)b * L + c * CCH) * D;
  for (int r = 0; r < CCH; ++r) {
    const float* y1 = yb[(r + 1) & 1];
    const float* y2 = yb[r & 1];
    float acc = 0.f;
    #pragma unroll
    for (int i = 0; i < 16; ++i)
      acc += m0[i] * y1[h * 16 + i] + m1[i] * y2[h * 16 + i];
    acc += __shfl_xor(acc, 32);
    float y = acc + Dl[r][o];
    __syncthreads();
    if (h == 0) { yb[r & 1][o] = y; op[r * D + o] = y; }
    __syncthreads();
  }
}

// ---------------------------------------------------------------- launch
extern "C" void kernel_launch(void* const* d_in, const int* in_sizes, int n_in,
                              void* d_out, int out_size, void* d_ws, size_t ws_size,
                              hipStream_t stream) {
  const float* u        = (const float*)d_in[0];
  const float* eig_vals = (const float*)d_in[1];
  const float* eig_vecs = (const float*)d_in[2];
  const float* m_u      = (const float*)d_in[3];
  const float* m_phi    = (const float*)d_in[4];
  const float* m_y      = (const float*)d_in[5];
  float* out = (float*)d_out;

  char* ws = (char*)d_ws;
  size_t off = 0;
  auto alloc = [&](size_t bytes) -> void* {
    void* p = ws + off;
    off += bytes;
    off = (off + 255) & ~(size_t)255;
    return p;
  };
  float2* tw   = (float2*)alloc((size_t)NFFT * sizeof(float2));           // 32 KB
  float2* uTp  = (float2*)alloc((size_t)B * 16 * L * sizeof(float2));     // 8.4 MB
  float2* Vf   = (float2*)alloc((size_t)D * UST * sizeof(float2));        // 0.5 MB
  float2* Wm   = (float2*)alloc((size_t)NH * D * D * sizeof(float2));     // 16.8 MB
  float2* Ubuf = (float2*)alloc((size_t)B * D * UST * sizeof(float2));    // 16.8 MB
  float2* Qbuf = (float2*)alloc((size_t)B * D * UST * sizeof(float2));    // 16.8 MB
  float*  Tc   = (float*)alloc(64 * 64 * sizeof(float));
  float*  shat = (float*)alloc((size_t)B * NCH * 64 * sizeof(float));
  float*  sinb = (float*)alloc((size_t)B * NCH * 64 * sizeof(float));
  // aliases: dT reuses uTp (dead after k_fft_fwd); delta reuses Ubuf (dead after k_mix)
  float* dT    = (float*)uTp;
  float* delta = (float*)Ubuf;

  k_tr     <<<dim3(L / 64 + 2, B), 256, 0, stream>>>(u, uTp, tw);
  k_fft_fwd<<<528, 512, 0, stream>>>(uTp, eig_vecs, eig_vals, tw, Ubuf, Vf);
  k_w      <<<(NH + KWFT - 1) / KWFT, 256, 0, stream>>>(Vf, m_phi, Wm);
  k_mix    <<<dim3((NH + FT - 1) / FT, 2), 256, 0, stream>>>(Ubuf, Wm, Qbuf);
  k_ifft   <<<B * 16, 512, 0, stream>>>(Qbuf, tw, dT);
  k_ar     <<<dim3(L / TT, B), 256, 0, stream>>>(dT, u, m_u, delta);
  k_tc     <<<1, 1024, 0, stream>>>(m_y, Tc);
  k_scanA  <<<dim3(NCH, B), 64, 0, stream>>>(delta, m_y, shat);
  k_scanB  <<<B, 64, 0, stream>>>(Tc, shat, sinb);
  k_scanC  <<<dim3(NCH, B), 64, 0, stream>>>(delta, m_y, sinb, out);
}